// Round 19
// baseline (233.845 us; speedup 1.0000x reference)
//
#include <hip/hip_runtime.h>

typedef unsigned short u16;
typedef __bf16 bf16x8 __attribute__((ext_vector_type(8)));
typedef short s16x4 __attribute__((ext_vector_type(4)));
typedef float f32x4 __attribute__((ext_vector_type(4)));

#define SCALE_ATT 0.0625f   // C^-0.5 = 1/16

// f32 -> bf16 RNE via native cast (one v_cvt_pk_bf16_f32; m240).
static __device__ __forceinline__ u16 f2b(float f) {
    __bf16 h = (__bf16)f;
    union { __bf16 b; u16 u; } v; v.b = h;
    return v.u;
}
static __device__ __forceinline__ float b2f(u16 h) {
    union { unsigned u; float f; } v; v.u = ((unsigned)h) << 16;
    return v.f;
}

#if defined(__has_builtin)
#if __has_builtin(__builtin_amdgcn_mfma_f32_16x16x16bf16_1k)
#define HAVE_MFMA16 1
#endif
#if __has_builtin(__builtin_amdgcn_exp2f)
#define EXP2(x) __builtin_amdgcn_exp2f(x)
#endif
#if __has_builtin(__builtin_amdgcn_rcpf)
#define RCP(x) __builtin_amdgcn_rcpf(x)
#endif
#if __has_builtin(__builtin_amdgcn_global_load_lds)
#define HAVE_GLOADLDS 1
#endif
#endif
#ifndef EXP2
#define EXP2(x) exp2f(x)
#endif
#ifndef RCP
#define RCP(x) (1.0f / (x))
#endif

static __device__ __forceinline__ f32x4 mfma16(s16x4 a, s16x4 b, f32x4 c) {
#ifdef HAVE_MFMA16
    return __builtin_amdgcn_mfma_f32_16x16x16bf16_1k(a, b, c, 0, 0, 0);
#else
    f32x4 d;
    asm volatile("v_mfma_f32_16x16x16_bf16 %0, %1, %2, %3\n\ts_nop 7\n\ts_nop 7"
                 : "=v"(d) : "v"(a), "v"(b), "v"(c));
    return d;
#endif
}

#ifdef HAVE_GLOADLDS
static __device__ __forceinline__ void gload16(const u16* g, u16* l) {
    __builtin_amdgcn_global_load_lds(
        (const __attribute__((address_space(1))) void*)g,
        (__attribute__((address_space(3))) void*)l, 16, 0, 0);
}
#endif

// tanh-form gelu: ~9 VALU vs ~30 for ocml erff; |err vs exact| <= 3e-3.
static __device__ __forceinline__ float gelu_fast(float v) {
    float v2 = v * v;
    float w = fmaf(v2, 0.044715f, 1.0f);
    float arg = v * w * 2.30211754f;      // 2 * 0.7978845608 * log2(e)
    float e = EXP2(arg);
    float r = RCP(e + 1.0f);
    return fmaf(-v, r, v);                 // v * (1 - r)
}

// ---------------------------------------------------------------------------
// All three weight transposes in one launch (segmented flat index).
__global__ void wtrans3_kernel(const float* __restrict__ qkv_w,
                               const float* __restrict__ w1,
                               const float* __restrict__ w2,
                               u16* __restrict__ wt_qkv,
                               u16* __restrict__ wt_m1,
                               u16* __restrict__ wt_m2) {
    int i = blockIdx.x * 256 + threadIdx.x;
    if (i < 196608) {                       // qkv_w: [256][768] -> [768][256]
        int r = i / 768, c = i % 768;
        wt_qkv[(size_t)c * 256 + r] = f2b(qkv_w[i]);
    } else if (i < 458752) {                // w1: [256][1024] -> [1024][256]
        int j = i - 196608;
        int r = j >> 10, c = j & 1023;
        wt_m1[(size_t)c * 256 + r] = f2b(w1[j]);
    } else if (i < 720896) {                // w2: [1024][256] -> [256][1024]
        int j = i - 458752;
        int r = j >> 8, c = j & 255;
        wt_m2[(size_t)c * 1024 + r] = f2b(w2[j]);
    }
}

// ---------------------------------------------------------------------------
// LN1 + NCHW->NHWC transpose. Block = (n,y). Writes xp (raw x, NHWC bf16),
// ln1 (bf16 NHWC), and per-(y, window-col) pooled partial sums (fp32 LN vals).
__global__ __launch_bounds__(256) void ln_xpose_kernel(
    const float* __restrict__ x, const float* __restrict__ g, const float* __restrict__ b,
    u16* __restrict__ xp, u16* __restrict__ ln1, float* __restrict__ pool_part) {
    __shared__ float xs[256][65];
    __shared__ float ps[4][64], ps2[4][64];
    __shared__ float mvmu[64], mvrs[64];
    int nb = blockIdx.x; int n = nb >> 6, y = nb & 63;
    int t = threadIdx.x;
    const float4* src = (const float4*)(x + ((size_t)(n * 256 + t) * 64 + y) * 64);
    for (int x4 = 0; x4 < 16; ++x4) {
        float4 v = src[x4];
        xs[t][x4 * 4 + 0] = v.x; xs[t][x4 * 4 + 1] = v.y;
        xs[t][x4 * 4 + 2] = v.z; xs[t][x4 * 4 + 3] = v.w;
    }
    __syncthreads();
    int part = t >> 6, l = t & 63;
    float s1 = 0.f, s2 = 0.f;
    for (int c = 0; c < 64; ++c) { float v = xs[part * 64 + c][l]; s1 += v; s2 += v * v; }
    ps[part][l] = s1; ps2[part][l] = s2;
    __syncthreads();
    if (t < 64) {
        float su = ps[0][t] + ps[1][t] + ps[2][t] + ps[3][t];
        float sq = ps2[0][t] + ps2[1][t] + ps2[2][t] + ps2[3][t];
        float mu = su * (1.f / 256.f);
        float var = sq * (1.f / 256.f) - mu * mu;
        mvmu[t] = mu; mvrs[t] = rsqrtf(var + 1e-6f);
    }
    __syncthreads();
    float gc = g[t], bc = b[t];
    size_t tokbase = (size_t)nb * 64;
    float pw = 0.f;
    for (int xx = 0; xx < 64; ++xx) {
        float raw = xs[t][xx];
        float val = (raw - mvmu[xx]) * mvrs[xx] * gc + bc;
        size_t tok = tokbase + xx;
        xp[tok * 256 + t] = f2b(raw);
        ln1[tok * 256 + t] = f2b(val);
        pw += val;
        if ((xx & 7) == 7) {
            pool_part[((size_t)nb * 8 + (xx >> 3)) * 256 + t] = pw;
            pw = 0.f;
        }
    }
}

// pooled[n][p][c] = mean over 64 window pixels (from y-row partials)
__global__ void pool_reduce_kernel(const float* __restrict__ pool_part,
                                   float* __restrict__ pooled) {
    int nb = blockIdx.x; int n = nb >> 6, p = nb & 63;
    int wi = p >> 3, wj = p & 7;
    int t = threadIdx.x;
    float s = 0.f;
    for (int r = 0; r < 8; ++r)
        s += pool_part[((size_t)((n * 64 + wi * 8 + r) * 8 + wj)) * 256 + t];
    pooled[(size_t)nb * 256 + t] = s * (1.f / 64.f);
}

// q_win/k_win = pooled @ Wq/Wk + b  (fp32, tiny). qk_win[nb][0:256]=q, [256:512]=k
__global__ void qkwin_kernel(const float* __restrict__ pooled,
                             const float* __restrict__ qkv_w, const float* __restrict__ qkv_b,
                             float* __restrict__ qk_win) {
    __shared__ float pr[256];
    int nb = blockIdx.x; int t = threadIdx.x;
    pr[t] = pooled[(size_t)nb * 256 + t];
    __syncthreads();
    float aq = qkv_b[t], ak = qkv_b[256 + t];
    for (int k = 0; k < 256; ++k) {
        float pv = pr[k];
        aq += pv * qkv_w[(size_t)k * 768 + t];
        ak += pv * qkv_w[(size_t)k * 768 + 256 + t];
    }
    qk_win[(size_t)nb * 512 + t] = aq;
    qk_win[(size_t)nb * 512 + 256 + t] = ak;
}

// top-4 window routing (sequential argmax == jax.lax.top_k tie rule: lowest idx)
__global__ void routing_kernel(const float* __restrict__ qk_win, int* __restrict__ idxp) {
    __shared__ float lg_[64];
    int nb = blockIdx.x; int n = nb >> 6;
    int t = threadIdx.x;  // 64 threads
    const float* qw = qk_win + (size_t)nb * 512;
    const float* kw = qk_win + (size_t)(n * 64 + t) * 512 + 256;
    float s = 0.f;
    for (int c = 0; c < 256; ++c) s += qw[c] * kw[c];
    lg_[t] = s * SCALE_ATT;
    __syncthreads();
    if (t == 0) {
        for (int j = 0; j < 4; ++j) {
            float best = -INFINITY; int bi = 0;
            for (int q = 0; q < 64; ++q) if (lg_[q] > best) { best = lg_[q]; bi = q; }
            idxp[nb * 4 + j] = bi;
            lg_[bi] = -INFINITY;
        }
    }
}

// ---------------------------------------------------------------------------
// bf16 GEMM: 128x128 tile, BK=32, 4 waves, 4x4 16x16 frags/wave.
// R19: 3-DEEP prefetch on the 4-slot LDS ring (32 KB). HBM-miss latency is
// ~900 cyc (m126); one compute phase is ~230 cyc. R12/R18 prefetched only
// 1 phase ahead -> every K-step stalled ~600 cyc on vmcnt (why MfmaUtil=12%
// and all barrier/schedule tweaks were null). Prologue stages tiles 0..2;
// phase tk issues tile tk+3, waits vmcnt(12) (= tiles tk+1..tk+3 in flight,
// tile tk landed). Epilogue drains 8/4/0. Slot (tk+3)&3 held tile tk-1 whose
// reads finished at phase tk-1's trailing barrier.
// Epilogue fully unrolled (rule #20).
// EPI 0: ->bf16. EPI 1: gelu(tanh-form)->bf16.
// EPI 2 (fused): yv = b2f(resid_in bf16) + gamma*v -> NCHW f32 via LDS xpose.
template <int EPI>
__global__ __launch_bounds__(256) void gemm_kernel(
    const u16* __restrict__ A, const u16* __restrict__ Bt,
    const float* __restrict__ bias, u16* __restrict__ outb,
    int M, int Nn, int K,
    const u16* __restrict__ resid_in, const float* __restrict__ gamma,
    float* __restrict__ resid_out) {
    __shared__ u16 smem[16384];    // As ring 8192 + Bs ring 8192 (4 slots x 2KB... 4 x 4KB)
    u16* As = smem;                // 4 slots x 4096 u16? -> As 4*2048... see below
    u16* Bs = smem + 8192;
    // ring slot = 2048 u16 (128 rows x 16? no) -- each tile = 128x32 = 4096 u16.
    // As ring needs 4 slots x 4096 u16 = 16384 u16 = 32KB. Total 64KB too big.
    // Use 4 slots with As slot 2048... CORRECTION: tile is 4096 u16 = 8KB.
    // As ring 4x8KB = 32KB + Bs 32KB = 64KB. Keep (2 blocks/CU, same as R18).
    int t = threadIdx.x;
    int rowBase = blockIdx.x * 128, colBase = blockIdx.y * 128;
    int wid = t >> 6, lane = t & 63;
    int wr = (wid >> 1) * 64, wc = (wid & 1) * 64;
    int lr = lane & 15, g = lane >> 4;
    f32x4 acc[4][4] = {};

    int rA0 = wid * 32 + (lane >> 2);
    int rA1 = rA0 + 16;
    int cs0 = (lane & 3) ^ ((rA0 >> 1) & 3);
    int cs1 = (lane & 3) ^ ((rA1 >> 1) & 3);
    const u16* gA0 = A + (size_t)(rowBase + rA0) * K + cs0 * 8;
    const u16* gA1 = A + (size_t)(rowBase + rA1) * K + cs1 * 8;
    const u16* gB0 = Bt + (size_t)(colBase + rA0) * K + cs0 * 8;
    const u16* gB1 = Bt + (size_t)(colBase + rA1) * K + cs1 * 8;
    int cSwz = (g * 16) ^ (((lr >> 1) & 3) << 4);
    const int NT = K >> 5;                 // >= 8 for all our K

#ifdef HAVE_GLOADLDS
    // NOTE: ring lives in a 64KB dynamic view: reuse smem[16384] as the first
    // 32KB and extend with a second static array to keep 64KB total.
    __shared__ u16 smem2[16384];
    u16* ringA = smem;                     // 4 slots x 4096 u16 (8KB)
    u16* ringB = smem2;
    u16* lA0 = &ringA[(wid * 2 + 0) * 512];
    u16* lA1 = &ringA[(wid * 2 + 1) * 512];
    u16* lB0 = &ringB[(wid * 2 + 0) * 512];
    u16* lB1 = &ringB[(wid * 2 + 1) * 512];
    // prologue: tiles 0,1,2 -> slots 0,1,2
    #pragma unroll
    for (int p = 0; p < 3; ++p) {
        int ko = p << 5, bo = p * 4096;
        gload16(gA0 + ko, lA0 + bo); gload16(gA1 + ko, lA1 + bo);
        gload16(gB0 + ko, lB0 + bo); gload16(gB1 + ko, lB1 + bo);
    }
    for (int tk = 0; tk < NT; ++tk) {
        if (tk + 3 < NT) {
            int ko = (tk + 3) << 5;
            int bo = ((tk + 3) & 3) * 4096;
            gload16(gA0 + ko, lA0 + bo); gload16(gA1 + ko, lA1 + bo);
            gload16(gB0 + ko, lB0 + bo); gload16(gB1 + ko, lB1 + bo);
            asm volatile("s_waitcnt vmcnt(12)" ::: "memory");  // tile tk landed
        } else if (tk + 2 < NT) {
            asm volatile("s_waitcnt vmcnt(8)" ::: "memory");
        } else if (tk + 1 < NT) {
            asm volatile("s_waitcnt vmcnt(4)" ::: "memory");
        } else {
            asm volatile("s_waitcnt vmcnt(0)" ::: "memory");
        }
        __builtin_amdgcn_s_barrier();
        asm volatile("" ::: "memory");
        const char* pAc = (const char*)ringA + ((tk & 3) << 13);
        const char* pBc = (const char*)ringB + ((tk & 3) << 13);
        bf16x8 af[4], bfr[4];
        #pragma unroll
        for (int m = 0; m < 4; ++m)
            af[m] = *(const bf16x8*)(pAc + (wr + m * 16 + lr) * 64 + cSwz);
        #pragma unroll
        for (int nn = 0; nn < 4; ++nn)
            bfr[nn] = *(const bf16x8*)(pBc + (wc + nn * 16 + lr) * 64 + cSwz);
        #pragma unroll
        for (int m = 0; m < 4; ++m)
            #pragma unroll
            for (int nn = 0; nn < 4; ++nn)
                acc[m][nn] = __builtin_amdgcn_mfma_f32_16x16x32_bf16(af[m], bfr[nn], acc[m][nn], 0, 0, 0);
        asm volatile("" ::: "memory");
        __builtin_amdgcn_s_barrier();      // reads of slot tk done -> reusable
    }
#else
    u16* lA0 = &As[(wid * 2 + 0) * 512];
    u16* lA1 = &As[(wid * 2 + 1) * 512];
    u16* lB0 = &Bs[(wid * 2 + 0) * 512];
    u16* lB1 = &Bs[(wid * 2 + 1) * 512];
    const char* pAc = (const char*)As;
    const char* pBc = (const char*)Bs;
    for (int tk = 0; tk < NT; ++tk) {
        int koff = tk << 5;
        float4 a0 = *(const float4*)(gA0 + koff);
        float4 a1 = *(const float4*)(gA1 + koff);
        float4 b0 = *(const float4*)(gB0 + koff);
        float4 b1 = *(const float4*)(gB1 + koff);
        __syncthreads();
        *(float4*)&lA0[lane * 8] = a0;
        *(float4*)&lA1[lane * 8] = a1;
        *(float4*)&lB0[lane * 8] = b0;
        *(float4*)&lB1[lane * 8] = b1;
        __syncthreads();
        bf16x8 af[4], bfr[4];
        #pragma unroll
        for (int m = 0; m < 4; ++m)
            af[m] = *(const bf16x8*)(pAc + (wr + m * 16 + lr) * 64 + cSwz);
        #pragma unroll
        for (int nn = 0; nn < 4; ++nn)
            bfr[nn] = *(const bf16x8*)(pBc + (wc + nn * 16 + lr) * 64 + cSwz);
        #pragma unroll
        for (int m = 0; m < 4; ++m)
            #pragma unroll
            for (int nn = 0; nn < 4; ++nn)
                acc[m][nn] = __builtin_amdgcn_mfma_f32_16x16x32_bf16(af[m], bfr[nn], acc[m][nn], 0, 0, 0);
        __syncthreads();
    }
#endif
    if constexpr (EPI == 2) {
        // fused residual + NCHW writeout via LDS transpose
        int n = rowBase >> 12;
        int y0 = (rowBase >> 6) & 63;
        float* ts = (float*)smem;          // [64 ch][128 tok], XOR-swizzled rows
        #pragma unroll
        for (int half = 0; half < 2; ++half) {
            __syncthreads();
            if ((wid & 1) == half) {
                #pragma unroll
                for (int m = 0; m < 4; ++m)
                    #pragma unroll
                    for (int nn = 0; nn < 4; ++nn) {
                        int colL = nn * 16 + lr;
                        int col = colBase + half * 64 + colL;
                        float bcol = bias[col];
                        float gcol = gamma[col];
                        int s = ((colL & 7) << 2) | ((colL >> 3) & 1);
                        #pragma unroll
                        for (int r = 0; r < 4; ++r) {
                            int rowIdx = wr + m * 16 + g * 4 + r;
                            float v = acc[m][nn][r] + bcol;
                            float yv = b2f(resid_in[(size_t)(rowBase + rowIdx) * 256 + col]) + gcol * v;
                            ts[colL * 128 + (rowIdx ^ s)] = yv;
                        }
                    }
            }
            __syncthreads();
            #pragma unroll
            for (int j = 0; j < 16; ++j) {
                int ch = wid * 16 + j;
                int s = ((ch & 7) << 2) | ((ch >> 3) & 1);
                float v0 = ts[ch * 128 + (lane ^ s)];
                float v1 = ts[ch * 128 + ((64 + lane) ^ s)];
                float* gb = resid_out + ((size_t)(n * 256 + colBase + half * 64 + ch) * 64 + y0) * 64;
                gb[lane] = v0;
                gb[64 + lane] = v1;
            }
        }
    } else {
        #pragma unroll
        for (int m = 0; m < 4; ++m)
            #pragma unroll
            for (int nn = 0; nn < 4; ++nn) {
                int col = colBase + wc + nn * 16 + lr;
                float bcol = bias[col];
                #pragma unroll
                for (int r = 0; r < 4; ++r) {
                    int row = rowBase + wr + m * 16 + g * 4 + r;
                    float v = acc[m][nn][r] + bcol;
                    if constexpr (EPI == 0) {
                        outb[(size_t)row * Nn + col] = f2b(v);
                    } else {
                        outb[(size_t)row * Nn + col] = f2b(gelu_fast(v));
                    }
                }
            }
    }
}

// ---------------------------------------------------------------------------
// MERGED attn + lepe mega-kernel. Grid (512, 12), 512 threads.
//   blockIdx.y < 8 : routed window attention head-pair hg = blockIdx.y
//   blockIdx.y >= 8: 5x5 depthwise lepe conv, ch-group cg = blockIdx.y - 8
// Best measured configuration (R14: 227.7 us).
__global__ __launch_bounds__(512) void attn_lepe_kernel(
    const u16* __restrict__ qkv, const int* __restrict__ idxp,
    const float* __restrict__ lw, const float* __restrict__ lb,
    u16* __restrict__ attn_out, u16* __restrict__ lepe_out) {
    __shared__ __align__(16) char smem_[40960];
    int t = threadIdx.x;
    if (blockIdx.y >= 8) {
        // ---- lepe path (512 threads: 8 x-positions per thread) ----
        u16 (*vt)[64][64] = (u16 (*)[64][64])smem_;   // [5][64][64] = 40960 B
        int nb = blockIdx.x, cg = blockIdx.y - 8;
        int n = nb >> 6, y = nb & 63;
        {   // stage: thread = (x, cseg); 1 float4 per row x 5 rows
            int xs = t >> 3, cs = t & 7;
            #pragma unroll
            for (int r = 0; r < 5; ++r) {
                int yy = y - 2 + r;
                bool ok = (yy >= 0 && yy <= 63);
                float4 v = {0.f, 0.f, 0.f, 0.f};
                if (ok)
                    v = *(const float4*)(qkv +
                        ((size_t)((n * 64 + yy) * 64 + xs)) * 768 + 512 + cg * 64 + cs * 8);
                *(float4*)&vt[r][xs][cs * 8] = v;
            }
        }
        __syncthreads();
        int c = t & 63, x0 = (t >> 6) * 8;
        float wv[25];
        #pragma unroll
        for (int i = 0; i < 25; ++i) wv[i] = lw[i * 256 + cg * 64 + c];
        float bc = lb[cg * 64 + c];
        float win[5][5];
        #pragma unroll
        for (int r = 0; r < 5; ++r)
            #pragma unroll
            for (int j = 0; j < 4; ++j) {
                int x2 = x0 - 2 + j;
                win[r][j] = (x2 >= 0) ? b2f(vt[r][x2][c]) : 0.f;
            }
        #pragma unroll
        for (int xi = 0; xi < 8; ++xi) {
            int xx = x0 + xi;
            int xl = xx + 2;
            #pragma unroll
            for (int r = 0; r < 5; ++r)
                win[r][4] = (xl <= 63) ? b2f(vt[r][xl][c]) : 0.f;
            float s = bc;
            #pragma unroll
            for (int r = 0; r < 5; ++r)
                #pragma unroll
                for (int j = 0; j < 5; ++j)
                    s = fmaf(wv[r * 5 + j], win[r][j], s);
            lepe_out[((size_t)nb * 64 + xx) * 256 + cg * 64 + c] = f2b(s);
            #pragma unroll
            for (int r = 0; r < 5; ++r)
                #pragma unroll
                for (int j = 0; j < 4; ++j)
                    win[r][j] = win[r][j + 1];
        }
        return;
    }
    // ---- attn path (unchanged internals) ----
    u16 (*qs)[36]   = (u16 (*)[36])smem_;              // [64][36] u16 = 4608 B
    u16 (*ks)[36]   = (u16 (*)[36])(smem_ + 4608);     // [256][36] u16 = 18432 B
    u16 (*vts)[256] = (u16 (*)[256])(smem_ + 23040);   // [32][256] u16 = 16384 B
    float (*os)[36] = (float (*)[36])(smem_ + 4608);   // alias ks: [64][36] f32
    int nb = blockIdx.x, hg = blockIdx.y;
    int n = nb >> 6, p = nb & 63;
    int y0 = (p >> 3) * 8, x0 = (p & 7) * 8;
    int w0 = idxp[nb * 4 + 0], w1 = idxp[nb * 4 + 1];
    int w2 = idxp[nb * 4 + 2], w3 = idxp[nb * 4 + 3];
    {   // stage Q: 64 tok x 32 ch, 8B per thread
        int tok = t >> 3, seg = t & 7;
        int tokg = (n * 64 + y0 + (tok >> 3)) * 64 + x0 + (tok & 7);
        *(uint2*)&qs[tok][seg * 4] =
            *(const uint2*)(qkv + (size_t)tokg * 768 + hg * 32 + seg * 4);
    }
    {   // stage K (rows, 4x uint2) and V (transposed+swizzled): 32B per thread each
        int key = t & 255, half = t >> 8;
        int ws = (key >> 6) == 0 ? w0 : (key >> 6) == 1 ? w1 : (key >> 6) == 2 ? w2 : w3;
        int kp = key & 63;
        int tokk = (n * 64 + (ws >> 3) * 8 + (kp >> 3)) * 64 + (ws & 7) * 8 + (kp & 7);
        const u16* kbase = qkv + (size_t)tokk * 768 + 256 + hg * 32 + half * 16;
        *(uint2*)&ks[key][half * 16 + 0]  = *(const uint2*)(kbase + 0);
        *(uint2*)&ks[key][half * 16 + 4]  = *(const uint2*)(kbase + 4);
        *(uint2*)&ks[key][half * 16 + 8]  = *(const uint2*)(kbase + 8);
        *(uint2*)&ks[key][half * 16 + 12] = *(const uint2*)(kbase + 12);
        const u16* vbase = kbase + 256;
        union { float4 f[2]; u16 u[16]; } vu;
        vu.f[0] = *(const float4*)vbase;
        vu.f[1] = *(const float4*)(vbase + 8);
        #pragma unroll
        for (int c2 = 0; c2 < 16; ++c2)
            vts[half * 16 + c2][key ^ (c2 << 2)] = vu.u[c2];
    }
    __syncthreads();

    int wid = t >> 6, lane = t & 63, lr = lane & 15, g = lane >> 4;
    int hh = wid & 1, q0 = (wid >> 1) * 16, c0 = hh * 16;
    f32x4 zf4 = {0.f, 0.f, 0.f, 0.f};
    s16x4 qf = *(const s16x4*)&qs[q0 + lr][c0 + g * 4];
    f32x4 sacc[16];
    __builtin_amdgcn_s_setprio(1);
    #pragma unroll
    for (int kt = 0; kt < 16; ++kt) {
        s16x4 kf = *(const s16x4*)&ks[kt * 16 + lr][c0 + g * 4];
        sacc[kt] = mfma16(kf, qf, zf4);
    }
    __builtin_amdgcn_s_setprio(0);
    float mx = fmaxf(fmaxf(sacc[0][0], sacc[0][1]), fmaxf(sacc[0][2], sacc[0][3]));
    #pragma unroll
    for (int kt = 1; kt < 16; ++kt) {
        mx = fmaxf(mx, fmaxf(sacc[kt][0], sacc[kt][1]));
        mx = fmaxf(mx, fmaxf(sacc[kt][2], sacc[kt][3]));
    }
    mx = fmaxf(mx, __shfl_xor(mx, 16, 64));
    mx = fmaxf(mx, __shfl_xor(mx, 32, 64));
    const float k1 = 0.09016844005556021f;  // SCALE_ATT * log2(e)
    float negmk = -mx * k1;
    float dsum = 0.f;
    s16x4 pf[16];
    #pragma unroll
    for (int kt = 0; kt < 16; ++kt) {
        float e0 = EXP2(fmaf(sacc[kt][0], k1, negmk));
        float e1 = EXP2(fmaf(sacc[kt][1], k1, negmk));
        float e2 = EXP2(fmaf(sacc[kt][2], k1, negmk));
        float e3 = EXP2(fmaf(sacc[kt][3], k1, negmk));
        dsum += (e0 + e1) + (e2 + e3);
        union { unsigned u[2]; s16x4 s; } pk;
        asm("v_cvt_pk_bf16_f32 %0, %1, %2" : "=v"(pk.u[0]) : "v"(e0), "v"(e1));
        asm("v_cvt_pk_bf16_f32 %0, %1, %2" : "=v"(pk.u[1]) : "v"(e2), "v"(e3));
        pf[kt] = pk.s;
    }
    dsum += __shfl_xor(dsum, 16, 64);
    dsum += __shfl_xor(dsum, 32, 64);
    float rden = 1.f / dsum;
    __syncthreads();   // all ks reads done before os (alias) is written
    f32x4 o0 = zf4, o1 = zf4;
    __builtin_amdgcn_s_setprio(1);
    #pragma unroll
    for (int kt = 0; kt < 16; kt += 2) {
        s16x4 v0 = *(const s16x4*)&vts[c0 + lr][(kt * 16 + g * 4) ^ (lr << 2)];
        o0 = mfma16(v0, pf[kt], o0);
        s16x4 v1 = *(const s16x4*)&vts[c0 + lr][((kt + 1) * 16 + g * 4) ^ (lr << 2)];
        o1 = mfma16(v1, pf[kt + 1], o1);
    }
    __builtin_amdgcn_s_setprio(0);
    #pragma unroll
    for (int r = 0; r < 4; ++r)
        os[q0 + lr][c0 + g * 4 + r] = (o0[r] + o1[r]) * rden;
    __syncthreads();
    {   // coalesced bf16 writeout: 64 tok x 32 ch
        int tok = t >> 3, cs = (t & 7) * 4;
        int tokg = (n * 64 + y0 + (tok >> 3)) * 64 + x0 + (tok & 7);
        float f0 = os[tok][cs + 0], f1 = os[tok][cs + 1];
        float f2 = os[tok][cs + 2], f3 = os[tok][cs + 3];
        uint2 pk;
        asm("v_cvt_pk_bf16_f32 %0, %1, %2" : "=v"(pk.x) : "v"(f0), "v"(f1));
        asm("v_cvt_pk_bf16_f32 %0, %1, %2" : "=v"(pk.y) : "v"(f2), "v"(f3));
        *(uint2*)(attn_out + (size_t)tokg * 256 + hg * 32 + cs) = pk;
    }
}

// ---------------------------------------------------------------------------
// xp1 = xp + g1*(attn + lepe); LN2 -> z (bf16). Wave = one token, 4 ch/lane,
// bf16x4 vector loads, pure shfl reduce (no LDS). xp1 written in place over xp.
__global__ __launch_bounds__(256) void resid1_ln2_kernel(
    const u16* __restrict__ xp, const u16* __restrict__ attn,
    const u16* __restrict__ lepe, const float* __restrict__ g1,
    const float* __restrict__ n2g, const float* __restrict__ n2b,
    u16* __restrict__ xp1, u16* __restrict__ z) {
    int t = threadIdx.x;
    int wid = t >> 6, lane = t & 63;
    size_t tok = (size_t)blockIdx.x * 4 + wid;
    size_t base = tok * 256 + lane * 4;
    uint2 xv = *(const uint2*)(xp + base);
    uint2 av = *(const uint2*)(attn + base);
    uint2 lv = *(const uint2*)(lepe + base);
    float4 g1v = *(const float4*)(g1 + lane * 4);
    float4 ngv = *(const float4*)(n2g + lane * 4);
    float4 nbv = *(const float4*)(n2b + lane * 4);
    const u16* xu = (const u16*)&xv;
    const u16* au = (const u16*)&av;
    const u16* lu = (const u16*)&lv;
    const float* g1f = (const float*)&g1v;
    const float* ngf = (const float*)&ngv;
    const float* nbf = (const float*)&nbv;
    float x1[4];
    float s1 = 0.f, s2 = 0.f;
    #pragma unroll
    for (int j = 0; j < 4; ++j) {
        float xx = b2f(xu[j]) + g1f[j] * (b2f(au[j]) + b2f(lu[j]));
        x1[j] = xx; s1 += xx; s2 += xx * xx;
    }
    #pragma unroll
    for (int off = 1; off < 64; off <<= 1) {
        s1 += __shfl_xor(s1, off, 64);
        s2 += __shfl_xor(s2, off, 64);
    }
    float mu = s1 * (1.f / 256.f);
    float var = s2 * (1.f / 256.f) - mu * mu;
    float rs = rsqrtf(var + 1e-6f);
    u16 zo[4], xo[4];
    #pragma unroll
    for (int j = 0; j < 4; ++j) {
        zo[j] = f2b((x1[j] - mu) * rs * ngf[j] + nbf[j]);
        xo[j] = f2b(x1[j]);
    }
    *(uint2*)(z + base) = *(uint2*)zo;
    *(uint2*)(xp1 + base) = *(uint2*)xo;
}

// ---------------------------------------------------------------------------
extern "C" void kernel_launch(void* const* d_in, const int* in_sizes, int n_in,
                              void* d_out, int out_size, void* d_ws, size_t ws_size,
                              hipStream_t stream) {
    (void)in_sizes; (void)n_in; (void)out_size; (void)ws_size;
    const float* x      = (const float*)d_in[0];
    const float* n1g    = (const float*)d_in[1];
    const float* n1b    = (const float*)d_in[2];
    const float* qkv_w  = (const float*)d_in[3];
    const float* qkv_b  = (const float*)d_in[4];
    const float* lepe_w = (const float*)d_in[5];
    const float* lepe_b = (const float*)d_in[6];
    const float* g1     = (const float*)d_in[7];
    const float* g2     = (const float*)d_in[8];
    const float* n2g    = (const float*)d_in[9];
    const float* n2b    = (const float*)d_in[10];
    const float* w1     = (const float*)d_in[11];
    const float* b1     = (const float*)d_in[12];
    const float* w2     = (const float*)d_in[13];
    const float* b2     = (const float*)d_in[14];
    float* outp = (float*)d_out;
    char* ws = (char*)d_ws;

    // workspace layout (total ~175 MB)
    u16*   xp_b      = (u16*)(ws + 0);              // 16,777,216 (bf16; region 33 MB)
    u16*   ln1       = (u16*)(ws + 33554432);       // 16,777,216
    u16*   qkv       = (u16*)(ws + 50331648);       // 50,331,648
    u16*   attn_b    = (u16*)(ws + 100663296);      // 16,777,216
    u16*   lepe      = (u16*)(ws + 134217728);      // 16,777,216
    u16*   zbuf      = (u16*)(ws + 150994944);      // 16,777,216
    float* pool_part = (float*)(ws + 167772160);    //  4,194,304
    float* pooled    = (float*)(ws + 171966464);    //    524,288
    float* qk_win    = (float*)(ws + 172490752);    //  1,048,576
    int*   idxb      = (int*)(ws + 173539328);      //      8,192
    u16*   wt_qkv    = (u16*)(ws + 173547520);      //    393,216
    u16*   wt_m1     = (u16*)(ws + 173940736);      //    524,288
    u16*   wt_m2     = (u16*)(ws + 174465024);      //    524,288  (end 174,989,312)
    u16*   hbuf      = ln1;       // [32768][1024] bf16 reuses ln1+qkv region (exactly 64 MB)

    wtrans3_kernel<<<2816, 256, 0, stream>>>(qkv_w, w1, w2, wt_qkv, wt_m1, wt_m2);

    ln_xpose_kernel<<<512, 256, 0, stream>>>(x, n1g, n1b, xp_b, ln1, pool_part);
    pool_reduce_kernel<<<512, 256, 0, stream>>>(pool_part, pooled);
    qkwin_kernel<<<512, 256, 0, stream>>>(pooled, qkv_w, qkv_b, qk_win);
    routing_kernel<<<512, 64, 0, stream>>>(qk_win, idxb);

    gemm_kernel<0><<<dim3(256, 6), 256, 0, stream>>>(
        ln1, wt_qkv, qkv_b, qkv, 32768, 768, 256, nullptr, nullptr, nullptr);

    attn_lepe_kernel<<<dim3(512, 12), 512, 0, stream>>>(
        qkv, idxb, lepe_w, lepe_b, attn_b, lepe);

    resid1_ln2_kernel<<<8192, 256, 0, stream>>>(xp_b, attn_b, lepe, g1, n2g, n2b, xp_b, zbuf);

    gemm_kernel<1><<<dim3(256, 8), 256, 0, stream>>>(
        zbuf, wt_m1, b1, hbuf, 32768, 1024, 256, nullptr, nullptr, nullptr);
    gemm_kernel<2><<<dim3(256, 2), 256, 0, stream>>>(
        hbuf, wt_m2, b2, nullptr, 32768, 256, 1024, xp_b, g2, outp);
}

// Round 20
// 227.586 us; speedup vs baseline: 1.0275x; 1.0275x over previous
//
#include <hip/hip_runtime.h>

typedef unsigned short u16;
typedef __bf16 bf16x8 __attribute__((ext_vector_type(8)));
typedef short s16x4 __attribute__((ext_vector_type(4)));
typedef float f32x4 __attribute__((ext_vector_type(4)));

#define SCALE_ATT 0.0625f   // C^-0.5 = 1/16

// f32 -> bf16 RNE via native cast (one v_cvt_pk_bf16_f32; m240).
static __device__ __forceinline__ u16 f2b(float f) {
    __bf16 h = (__bf16)f;
    union { __bf16 b; u16 u; } v; v.b = h;
    return v.u;
}
static __device__ __forceinline__ float b2f(u16 h) {
    union { unsigned u; float f; } v; v.u = ((unsigned)h) << 16;
    return v.f;
}

#if defined(__has_builtin)
#if __has_builtin(__builtin_amdgcn_mfma_f32_16x16x16bf16_1k)
#define HAVE_MFMA16 1
#endif
#if __has_builtin(__builtin_amdgcn_exp2f)
#define EXP2(x) __builtin_amdgcn_exp2f(x)
#endif
#if __has_builtin(__builtin_amdgcn_rcpf)
#define RCP(x) __builtin_amdgcn_rcpf(x)
#endif
#if __has_builtin(__builtin_amdgcn_global_load_lds)
#define HAVE_GLOADLDS 1
#endif
#endif
#ifndef EXP2
#define EXP2(x) exp2f(x)
#endif
#ifndef RCP
#define RCP(x) (1.0f / (x))
#endif

static __device__ __forceinline__ f32x4 mfma16(s16x4 a, s16x4 b, f32x4 c) {
#ifdef HAVE_MFMA16
    return __builtin_amdgcn_mfma_f32_16x16x16bf16_1k(a, b, c, 0, 0, 0);
#else
    f32x4 d;
    asm volatile("v_mfma_f32_16x16x16_bf16 %0, %1, %2, %3\n\ts_nop 7\n\ts_nop 7"
                 : "=v"(d) : "v"(a), "v"(b), "v"(c));
    return d;
#endif
}

#ifdef HAVE_GLOADLDS
static __device__ __forceinline__ void gload16(const u16* g, u16* l) {
    __builtin_amdgcn_global_load_lds(
        (const __attribute__((address_space(1))) void*)g,
        (__attribute__((address_space(3))) void*)l, 16, 0, 0);
}
#endif

// tanh-form gelu: ~9 VALU vs ~30 for ocml erff; |err vs exact| <= 3e-3.
static __device__ __forceinline__ float gelu_fast(float v) {
    float v2 = v * v;
    float w = fmaf(v2, 0.044715f, 1.0f);
    float arg = v * w * 2.30211754f;      // 2 * 0.7978845608 * log2(e)
    float e = EXP2(arg);
    float r = RCP(e + 1.0f);
    return fmaf(-v, r, v);                 // v * (1 - r)
}

// ---------------------------------------------------------------------------
// All three weight transposes in one launch (segmented flat index).
__global__ void wtrans3_kernel(const float* __restrict__ qkv_w,
                               const float* __restrict__ w1,
                               const float* __restrict__ w2,
                               u16* __restrict__ wt_qkv,
                               u16* __restrict__ wt_m1,
                               u16* __restrict__ wt_m2) {
    int i = blockIdx.x * 256 + threadIdx.x;
    if (i < 196608) {                       // qkv_w: [256][768] -> [768][256]
        int r = i / 768, c = i % 768;
        wt_qkv[(size_t)c * 256 + r] = f2b(qkv_w[i]);
    } else if (i < 458752) {                // w1: [256][1024] -> [1024][256]
        int j = i - 196608;
        int r = j >> 10, c = j & 1023;
        wt_m1[(size_t)c * 256 + r] = f2b(w1[j]);
    } else if (i < 720896) {                // w2: [1024][256] -> [256][1024]
        int j = i - 458752;
        int r = j >> 8, c = j & 255;
        wt_m2[(size_t)c * 1024 + r] = f2b(w2[j]);
    }
}

// ---------------------------------------------------------------------------
// LN1 + NCHW->NHWC transpose. Block = (n,y). Writes xp (raw x, NHWC bf16),
// ln1 (bf16 NHWC), and per-(y, window-col) pooled partial sums (fp32 LN vals).
__global__ __launch_bounds__(256) void ln_xpose_kernel(
    const float* __restrict__ x, const float* __restrict__ g, const float* __restrict__ b,
    u16* __restrict__ xp, u16* __restrict__ ln1, float* __restrict__ pool_part) {
    __shared__ float xs[256][65];
    __shared__ float ps[4][64], ps2[4][64];
    __shared__ float mvmu[64], mvrs[64];
    int nb = blockIdx.x; int n = nb >> 6, y = nb & 63;
    int t = threadIdx.x;
    const float4* src = (const float4*)(x + ((size_t)(n * 256 + t) * 64 + y) * 64);
    for (int x4 = 0; x4 < 16; ++x4) {
        float4 v = src[x4];
        xs[t][x4 * 4 + 0] = v.x; xs[t][x4 * 4 + 1] = v.y;
        xs[t][x4 * 4 + 2] = v.z; xs[t][x4 * 4 + 3] = v.w;
    }
    __syncthreads();
    int part = t >> 6, l = t & 63;
    float s1 = 0.f, s2 = 0.f;
    for (int c = 0; c < 64; ++c) { float v = xs[part * 64 + c][l]; s1 += v; s2 += v * v; }
    ps[part][l] = s1; ps2[part][l] = s2;
    __syncthreads();
    if (t < 64) {
        float su = ps[0][t] + ps[1][t] + ps[2][t] + ps[3][t];
        float sq = ps2[0][t] + ps2[1][t] + ps2[2][t] + ps2[3][t];
        float mu = su * (1.f / 256.f);
        float var = sq * (1.f / 256.f) - mu * mu;
        mvmu[t] = mu; mvrs[t] = rsqrtf(var + 1e-6f);
    }
    __syncthreads();
    float gc = g[t], bc = b[t];
    size_t tokbase = (size_t)nb * 64;
    float pw = 0.f;
    for (int xx = 0; xx < 64; ++xx) {
        float raw = xs[t][xx];
        float val = (raw - mvmu[xx]) * mvrs[xx] * gc + bc;
        size_t tok = tokbase + xx;
        xp[tok * 256 + t] = f2b(raw);
        ln1[tok * 256 + t] = f2b(val);
        pw += val;
        if ((xx & 7) == 7) {
            pool_part[((size_t)nb * 8 + (xx >> 3)) * 256 + t] = pw;
            pw = 0.f;
        }
    }
}

// pooled[n][p][c] = mean over 64 window pixels (from y-row partials)
__global__ void pool_reduce_kernel(const float* __restrict__ pool_part,
                                   float* __restrict__ pooled) {
    int nb = blockIdx.x; int n = nb >> 6, p = nb & 63;
    int wi = p >> 3, wj = p & 7;
    int t = threadIdx.x;
    float s = 0.f;
    for (int r = 0; r < 8; ++r)
        s += pool_part[((size_t)((n * 64 + wi * 8 + r) * 8 + wj)) * 256 + t];
    pooled[(size_t)nb * 256 + t] = s * (1.f / 64.f);
}

// q_win/k_win = pooled @ Wq/Wk + b  (fp32, tiny). qk_win[nb][0:256]=q, [256:512]=k
__global__ void qkwin_kernel(const float* __restrict__ pooled,
                             const float* __restrict__ qkv_w, const float* __restrict__ qkv_b,
                             float* __restrict__ qk_win) {
    __shared__ float pr[256];
    int nb = blockIdx.x; int t = threadIdx.x;
    pr[t] = pooled[(size_t)nb * 256 + t];
    __syncthreads();
    float aq = qkv_b[t], ak = qkv_b[256 + t];
    for (int k = 0; k < 256; ++k) {
        float pv = pr[k];
        aq += pv * qkv_w[(size_t)k * 768 + t];
        ak += pv * qkv_w[(size_t)k * 768 + 256 + t];
    }
    qk_win[(size_t)nb * 512 + t] = aq;
    qk_win[(size_t)nb * 512 + 256 + t] = ak;
}

// top-4 window routing (sequential argmax == jax.lax.top_k tie rule: lowest idx)
__global__ void routing_kernel(const float* __restrict__ qk_win, int* __restrict__ idxp) {
    __shared__ float lg_[64];
    int nb = blockIdx.x; int n = nb >> 6;
    int t = threadIdx.x;  // 64 threads
    const float* qw = qk_win + (size_t)nb * 512;
    const float* kw = qk_win + (size_t)(n * 64 + t) * 512 + 256;
    float s = 0.f;
    for (int c = 0; c < 256; ++c) s += qw[c] * kw[c];
    lg_[t] = s * SCALE_ATT;
    __syncthreads();
    if (t == 0) {
        for (int j = 0; j < 4; ++j) {
            float best = -INFINITY; int bi = 0;
            for (int q = 0; q < 64; ++q) if (lg_[q] > best) { best = lg_[q]; bi = q; }
            idxp[nb * 4 + j] = bi;
            lg_[bi] = -INFINITY;
        }
    }
}

// ---------------------------------------------------------------------------
// bf16 GEMM: 128x128 tile, BK=32, 4 waves, 4x4 16x16 frags/wave.
// 2-phase gload_lds pipeline (counted vmcnt(4), never 0 mid-loop).
// Epilogue fully unrolled (rule #20).
// EPI 0: ->bf16. EPI 1: gelu(tanh-form)->bf16.
// EPI 2 (fused): yv = b2f(resid_in bf16) + gamma*v, written DIRECTLY to NCHW
// f32 output via LDS tile transpose.
// Ledger (R10-R19): swizzle+gload null; 2-phase vmcnt -4; barrier-halving
// null; 3-deep ring -5 (occupancy); epilogue VALU diet -8 (real). This
// structure is at its practical plateau (~m97-class); only a 256^2 8-phase
// rewrite would go further.
template <int EPI>
__global__ __launch_bounds__(256) void gemm_kernel(
    const u16* __restrict__ A, const u16* __restrict__ Bt,
    const float* __restrict__ bias, u16* __restrict__ outb,
    int M, int Nn, int K,
    const u16* __restrict__ resid_in, const float* __restrict__ gamma,
    float* __restrict__ resid_out) {
    __shared__ u16 smem[16384];    // As(8192) + Bs(8192); reused as 32KB f32 tile
    u16* As = smem;
    u16* Bs = smem + 8192;
    int t = threadIdx.x;
    int rowBase = blockIdx.x * 128, colBase = blockIdx.y * 128;
    int wid = t >> 6, lane = t & 63;
    int wr = (wid >> 1) * 64, wc = (wid & 1) * 64;
    int lr = lane & 15, g = lane >> 4;
    f32x4 acc[4][4] = {};

    int rA0 = wid * 32 + (lane >> 2);
    int rA1 = rA0 + 16;
    int cs0 = (lane & 3) ^ ((rA0 >> 1) & 3);
    int cs1 = (lane & 3) ^ ((rA1 >> 1) & 3);
    const u16* gA0 = A + (size_t)(rowBase + rA0) * K + cs0 * 8;
    const u16* gA1 = A + (size_t)(rowBase + rA1) * K + cs1 * 8;
    const u16* gB0 = Bt + (size_t)(colBase + rA0) * K + cs0 * 8;
    const u16* gB1 = Bt + (size_t)(colBase + rA1) * K + cs1 * 8;
    u16* lA0 = &As[(wid * 2 + 0) * 512];
    u16* lA1 = &As[(wid * 2 + 1) * 512];
    u16* lB0 = &Bs[(wid * 2 + 0) * 512];
    u16* lB1 = &Bs[(wid * 2 + 1) * 512];

    int cSwz = (g * 16) ^ (((lr >> 1) & 3) << 4);
    const int NT = K >> 5;

#ifdef HAVE_GLOADLDS
    gload16(gA0, lA0);
    gload16(gA1, lA1);
    gload16(gB0, lB0);
    gload16(gB1, lB1);
    int cur = 0;
    for (int tk = 0; tk < NT; ++tk) {
        if (tk + 1 < NT) {
            int koff = (tk + 1) << 5;
            int bo = (cur ^ 1) << 12;
            gload16(gA0 + koff, lA0 + bo);
            gload16(gA1 + koff, lA1 + bo);
            gload16(gB0 + koff, lB0 + bo);
            gload16(gB1 + koff, lB1 + bo);
            asm volatile("s_waitcnt vmcnt(4)" ::: "memory");
        } else {
            asm volatile("s_waitcnt vmcnt(0)" ::: "memory");
        }
        __builtin_amdgcn_s_barrier();
        asm volatile("" ::: "memory");
        const char* pAc = (const char*)As + (cur << 13);
        const char* pBc = (const char*)Bs + (cur << 13);
        bf16x8 af[4], bfr[4];
        #pragma unroll
        for (int m = 0; m < 4; ++m)
            af[m] = *(const bf16x8*)(pAc + (wr + m * 16 + lr) * 64 + cSwz);
        #pragma unroll
        for (int nn = 0; nn < 4; ++nn)
            bfr[nn] = *(const bf16x8*)(pBc + (wc + nn * 16 + lr) * 64 + cSwz);
        #pragma unroll
        for (int m = 0; m < 4; ++m)
            #pragma unroll
            for (int nn = 0; nn < 4; ++nn)
                acc[m][nn] = __builtin_amdgcn_mfma_f32_16x16x32_bf16(af[m], bfr[nn], acc[m][nn], 0, 0, 0);
        asm volatile("" ::: "memory");
        __builtin_amdgcn_s_barrier();
        cur ^= 1;
    }
#else
    const char* pAc = (const char*)As;
    const char* pBc = (const char*)Bs;
    for (int tk = 0; tk < NT; ++tk) {
        int koff = tk << 5;
        float4 a0 = *(const float4*)(gA0 + koff);
        float4 a1 = *(const float4*)(gA1 + koff);
        float4 b0 = *(const float4*)(gB0 + koff);
        float4 b1 = *(const float4*)(gB1 + koff);
        __syncthreads();
        *(float4*)&lA0[lane * 8] = a0;
        *(float4*)&lA1[lane * 8] = a1;
        *(float4*)&lB0[lane * 8] = b0;
        *(float4*)&lB1[lane * 8] = b1;
        __syncthreads();
        bf16x8 af[4], bfr[4];
        #pragma unroll
        for (int m = 0; m < 4; ++m)
            af[m] = *(const bf16x8*)(pAc + (wr + m * 16 + lr) * 64 + cSwz);
        #pragma unroll
        for (int nn = 0; nn < 4; ++nn)
            bfr[nn] = *(const bf16x8*)(pBc + (wc + nn * 16 + lr) * 64 + cSwz);
        #pragma unroll
        for (int m = 0; m < 4; ++m)
            #pragma unroll
            for (int nn = 0; nn < 4; ++nn)
                acc[m][nn] = __builtin_amdgcn_mfma_f32_16x16x32_bf16(af[m], bfr[nn], acc[m][nn], 0, 0, 0);
        __syncthreads();
    }
#endif
    if constexpr (EPI == 2) {
        // fused residual + NCHW writeout via LDS transpose
        int n = rowBase >> 12;
        int y0 = (rowBase >> 6) & 63;
        float* ts = (float*)smem;          // [64 ch][128 tok], XOR-swizzled rows
        #pragma unroll
        for (int half = 0; half < 2; ++half) {
            if ((wid & 1) == half) {
                #pragma unroll
                for (int m = 0; m < 4; ++m)
                    #pragma unroll
                    for (int nn = 0; nn < 4; ++nn) {
                        int colL = nn * 16 + lr;
                        int col = colBase + half * 64 + colL;
                        float bcol = bias[col];
                        float gcol = gamma[col];
                        int s = ((colL & 7) << 2) | ((colL >> 3) & 1);
                        #pragma unroll
                        for (int r = 0; r < 4; ++r) {
                            int rowIdx = wr + m * 16 + g * 4 + r;
                            float v = acc[m][nn][r] + bcol;
                            float yv = b2f(resid_in[(size_t)(rowBase + rowIdx) * 256 + col]) + gcol * v;
                            ts[colL * 128 + (rowIdx ^ s)] = yv;
                        }
                    }
            }
            __syncthreads();
            #pragma unroll
            for (int j = 0; j < 16; ++j) {
                int ch = wid * 16 + j;
                int s = ((ch & 7) << 2) | ((ch >> 3) & 1);
                float v0 = ts[ch * 128 + (lane ^ s)];
                float v1 = ts[ch * 128 + ((64 + lane) ^ s)];
                float* gb = resid_out + ((size_t)(n * 256 + colBase + half * 64 + ch) * 64 + y0) * 64;
                gb[lane] = v0;
                gb[64 + lane] = v1;
            }
            __syncthreads();
        }
    } else {
        #pragma unroll
        for (int m = 0; m < 4; ++m)
            #pragma unroll
            for (int nn = 0; nn < 4; ++nn) {
                int col = colBase + wc + nn * 16 + lr;
                float bcol = bias[col];
                #pragma unroll
                for (int r = 0; r < 4; ++r) {
                    int row = rowBase + wr + m * 16 + g * 4 + r;
                    float v = acc[m][nn][r] + bcol;
                    if constexpr (EPI == 0) {
                        outb[(size_t)row * Nn + col] = f2b(v);
                    } else {
                        outb[(size_t)row * Nn + col] = f2b(gelu_fast(v));
                    }
                }
            }
    }
}

// ---------------------------------------------------------------------------
// MERGED attn + lepe mega-kernel. Grid (512, 12), 512 threads.
//   blockIdx.y < 8 : routed window attention head-pair hg = blockIdx.y
//   blockIdx.y >= 8: 5x5 depthwise lepe conv, ch-group cg = blockIdx.y - 8
// Best measured configuration (R14: 227.7 us; R17 repro: 228.8). R15 (flat
// interleave) and R16 (LDS diet + 16-role split) both failed to beat it.
__global__ __launch_bounds__(512) void attn_lepe_kernel(
    const u16* __restrict__ qkv, const int* __restrict__ idxp,
    const float* __restrict__ lw, const float* __restrict__ lb,
    u16* __restrict__ attn_out, u16* __restrict__ lepe_out) {
    __shared__ __align__(16) char smem_[40960];
    int t = threadIdx.x;
    if (blockIdx.y >= 8) {
        // ---- lepe path (512 threads: 8 x-positions per thread) ----
        u16 (*vt)[64][64] = (u16 (*)[64][64])smem_;   // [5][64][64] = 40960 B
        int nb = blockIdx.x, cg = blockIdx.y - 8;
        int n = nb >> 6, y = nb & 63;
        {   // stage: thread = (x, cseg); 1 float4 per row x 5 rows
            int xs = t >> 3, cs = t & 7;
            #pragma unroll
            for (int r = 0; r < 5; ++r) {
                int yy = y - 2 + r;
                bool ok = (yy >= 0 && yy <= 63);
                float4 v = {0.f, 0.f, 0.f, 0.f};
                if (ok)
                    v = *(const float4*)(qkv +
                        ((size_t)((n * 64 + yy) * 64 + xs)) * 768 + 512 + cg * 64 + cs * 8);
                *(float4*)&vt[r][xs][cs * 8] = v;
            }
        }
        __syncthreads();
        int c = t & 63, x0 = (t >> 6) * 8;
        float wv[25];
        #pragma unroll
        for (int i = 0; i < 25; ++i) wv[i] = lw[i * 256 + cg * 64 + c];
        float bc = lb[cg * 64 + c];
        float win[5][5];
        #pragma unroll
        for (int r = 0; r < 5; ++r)
            #pragma unroll
            for (int j = 0; j < 4; ++j) {
                int x2 = x0 - 2 + j;
                win[r][j] = (x2 >= 0) ? b2f(vt[r][x2][c]) : 0.f;
            }
        #pragma unroll
        for (int xi = 0; xi < 8; ++xi) {
            int xx = x0 + xi;
            int xl = xx + 2;
            #pragma unroll
            for (int r = 0; r < 5; ++r)
                win[r][4] = (xl <= 63) ? b2f(vt[r][xl][c]) : 0.f;
            float s = bc;
            #pragma unroll
            for (int r = 0; r < 5; ++r)
                #pragma unroll
                for (int j = 0; j < 5; ++j)
                    s = fmaf(wv[r * 5 + j], win[r][j], s);
            lepe_out[((size_t)nb * 64 + xx) * 256 + cg * 64 + c] = f2b(s);
            #pragma unroll
            for (int r = 0; r < 5; ++r)
                #pragma unroll
                for (int j = 0; j < 4; ++j)
                    win[r][j] = win[r][j + 1];
        }
        return;
    }
    // ---- attn path ----
    u16 (*qs)[36]   = (u16 (*)[36])smem_;              // [64][36] u16 = 4608 B
    u16 (*ks)[36]   = (u16 (*)[36])(smem_ + 4608);     // [256][36] u16 = 18432 B
    u16 (*vts)[256] = (u16 (*)[256])(smem_ + 23040);   // [32][256] u16 = 16384 B
    float (*os)[36] = (float (*)[36])(smem_ + 4608);   // alias ks: [64][36] f32
    int nb = blockIdx.x, hg = blockIdx.y;
    int n = nb >> 6, p = nb & 63;
    int y0 = (p >> 3) * 8, x0 = (p & 7) * 8;
    int w0 = idxp[nb * 4 + 0], w1 = idxp[nb * 4 + 1];
    int w2 = idxp[nb * 4 + 2], w3 = idxp[nb * 4 + 3];
    {   // stage Q: 64 tok x 32 ch, 8B per thread
        int tok = t >> 3, seg = t & 7;
        int tokg = (n * 64 + y0 + (tok >> 3)) * 64 + x0 + (tok & 7);
        *(uint2*)&qs[tok][seg * 4] =
            *(const uint2*)(qkv + (size_t)tokg * 768 + hg * 32 + seg * 4);
    }
    {   // stage K (rows, 4x uint2) and V (transposed+swizzled): 32B per thread each
        int key = t & 255, half = t >> 8;
        int ws = (key >> 6) == 0 ? w0 : (key >> 6) == 1 ? w1 : (key >> 6) == 2 ? w2 : w3;
        int kp = key & 63;
        int tokk = (n * 64 + (ws >> 3) * 8 + (kp >> 3)) * 64 + (ws & 7) * 8 + (kp & 7);
        const u16* kbase = qkv + (size_t)tokk * 768 + 256 + hg * 32 + half * 16;
        *(uint2*)&ks[key][half * 16 + 0]  = *(const uint2*)(kbase + 0);
        *(uint2*)&ks[key][half * 16 + 4]  = *(const uint2*)(kbase + 4);
        *(uint2*)&ks[key][half * 16 + 8]  = *(const uint2*)(kbase + 8);
        *(uint2*)&ks[key][half * 16 + 12] = *(const uint2*)(kbase + 12);
        const u16* vbase = kbase + 256;
        union { float4 f[2]; u16 u[16]; } vu;
        vu.f[0] = *(const float4*)vbase;
        vu.f[1] = *(const float4*)(vbase + 8);
        #pragma unroll
        for (int c2 = 0; c2 < 16; ++c2)
            vts[half * 16 + c2][key ^ (c2 << 2)] = vu.u[c2];
    }
    __syncthreads();

    int wid = t >> 6, lane = t & 63, lr = lane & 15, g = lane >> 4;
    int hh = wid & 1, q0 = (wid >> 1) * 16, c0 = hh * 16;
    f32x4 zf4 = {0.f, 0.f, 0.f, 0.f};
    s16x4 qf = *(const s16x4*)&qs[q0 + lr][c0 + g * 4];
    f32x4 sacc[16];
    __builtin_amdgcn_s_setprio(1);
    #pragma unroll
    for (int kt = 0; kt < 16; ++kt) {
        s16x4 kf = *(const s16x4*)&ks[kt * 16 + lr][c0 + g * 4];
        sacc[kt] = mfma16(kf, qf, zf4);
    }
    __builtin_amdgcn_s_setprio(0);
    float mx = fmaxf(fmaxf(sacc[0][0], sacc[0][1]), fmaxf(sacc[0][2], sacc[0][3]));
    #pragma unroll
    for (int kt = 1; kt < 16; ++kt) {
        mx = fmaxf(mx, fmaxf(sacc[kt][0], sacc[kt][1]));
        mx = fmaxf(mx, fmaxf(sacc[kt][2], sacc[kt][3]));
    }
    mx = fmaxf(mx, __shfl_xor(mx, 16, 64));
    mx = fmaxf(mx, __shfl_xor(mx, 32, 64));
    const float k1 = 0.09016844005556021f;  // SCALE_ATT * log2(e)
    float negmk = -mx * k1;
    float dsum = 0.f;
    s16x4 pf[16];
    #pragma unroll
    for (int kt = 0; kt < 16; ++kt) {
        float e0 = EXP2(fmaf(sacc[kt][0], k1, negmk));
        float e1 = EXP2(fmaf(sacc[kt][1], k1, negmk));
        float e2 = EXP2(fmaf(sacc[kt][2], k1, negmk));
        float e3 = EXP2(fmaf(sacc[kt][3], k1, negmk));
        dsum += (e0 + e1) + (e2 + e3);
        union { unsigned u[2]; s16x4 s; } pk;
        asm("v_cvt_pk_bf16_f32 %0, %1, %2" : "=v"(pk.u[0]) : "v"(e0), "v"(e1));
        asm("v_cvt_pk_bf16_f32 %0, %1, %2" : "=v"(pk.u[1]) : "v"(e2), "v"(e3));
        pf[kt] = pk.s;
    }
    dsum += __shfl_xor(dsum, 16, 64);
    dsum += __shfl_xor(dsum, 32, 64);
    float rden = 1.f / dsum;
    __syncthreads();   // all ks reads done before os (alias) is written
    f32x4 o0 = zf4, o1 = zf4;
    __builtin_amdgcn_s_setprio(1);
    #pragma unroll
    for (int kt = 0; kt < 16; kt += 2) {
        s16x4 v0 = *(const s16x4*)&vts[c0 + lr][(kt * 16 + g * 4) ^ (lr << 2)];
        o0 = mfma16(v0, pf[kt], o0);
        s16x4 v1 = *(const s16x4*)&vts[c0 + lr][((kt + 1) * 16 + g * 4) ^ (lr << 2)];
        o1 = mfma16(v1, pf[kt + 1], o1);
    }
    __builtin_amdgcn_s_setprio(0);
    #pragma unroll
    for (int r = 0; r < 4; ++r)
        os[q0 + lr][c0 + g * 4 + r] = (o0[r] + o1[r]) * rden;
    __syncthreads();
    {   // coalesced bf16 writeout: 64 tok x 32 ch
        int tok = t >> 3, cs = (t & 7) * 4;
        int tokg = (n * 64 + y0 + (tok >> 3)) * 64 + x0 + (tok & 7);
        float f0 = os[tok][cs + 0], f1 = os[tok][cs + 1];
        float f2 = os[tok][cs + 2], f3 = os[tok][cs + 3];
        uint2 pk;
        asm("v_cvt_pk_bf16_f32 %0, %1, %2" : "=v"(pk.x) : "v"(f0), "v"(f1));
        asm("v_cvt_pk_bf16_f32 %0, %1, %2" : "=v"(pk.y) : "v"(f2), "v"(f3));
        *(uint2*)(attn_out + (size_t)tokg * 256 + hg * 32 + cs) = pk;
    }
}

// ---------------------------------------------------------------------------
// xp1 = xp + g1*(attn + lepe); LN2 -> z (bf16). Wave = one token, 4 ch/lane,
// bf16x4 vector loads, pure shfl reduce (no LDS). xp1 written in place over xp.
__global__ __launch_bounds__(256) void resid1_ln2_kernel(
    const u16* __restrict__ xp, const u16* __restrict__ attn,
    const u16* __restrict__ lepe, const float* __restrict__ g1,
    const float* __restrict__ n2g, const float* __restrict__ n2b,
    u16* __restrict__ xp1, u16* __restrict__ z) {
    int t = threadIdx.x;
    int wid = t >> 6, lane = t & 63;
    size_t tok = (size_t)blockIdx.x * 4 + wid;
    size_t base = tok * 256 + lane * 4;
    uint2 xv = *(const uint2*)(xp + base);
    uint2 av = *(const uint2*)(attn + base);
    uint2 lv = *(const uint2*)(lepe + base);
    float4 g1v = *(const float4*)(g1 + lane * 4);
    float4 ngv = *(const float4*)(n2g + lane * 4);
    float4 nbv = *(const float4*)(n2b + lane * 4);
    const u16* xu = (const u16*)&xv;
    const u16* au = (const u16*)&av;
    const u16* lu = (const u16*)&lv;
    const float* g1f = (const float*)&g1v;
    const float* ngf = (const float*)&ngv;
    const float* nbf = (const float*)&nbv;
    float x1[4];
    float s1 = 0.f, s2 = 0.f;
    #pragma unroll
    for (int j = 0; j < 4; ++j) {
        float xx = b2f(xu[j]) + g1f[j] * (b2f(au[j]) + b2f(lu[j]));
        x1[j] = xx; s1 += xx; s2 += xx * xx;
    }
    #pragma unroll
    for (int off = 1; off < 64; off <<= 1) {
        s1 += __shfl_xor(s1, off, 64);
        s2 += __shfl_xor(s2, off, 64);
    }
    float mu = s1 * (1.f / 256.f);
    float var = s2 * (1.f / 256.f) - mu * mu;
    float rs = rsqrtf(var + 1e-6f);
    u16 zo[4], xo[4];
    #pragma unroll
    for (int j = 0; j < 4; ++j) {
        zo[j] = f2b((x1[j] - mu) * rs * ngf[j] + nbf[j]);
        xo[j] = f2b(x1[j]);
    }
    *(uint2*)(z + base) = *(uint2*)zo;
    *(uint2*)(xp1 + base) = *(uint2*)xo;
}

// ---------------------------------------------------------------------------
extern "C" void kernel_launch(void* const* d_in, const int* in_sizes, int n_in,
                              void* d_out, int out_size, void* d_ws, size_t ws_size,
                              hipStream_t stream) {
    (void)in_sizes; (void)n_in; (void)out_size; (void)ws_size;
    const float* x      = (const float*)d_in[0];
    const float* n1g    = (const float*)d_in[1];
    const float* n1b    = (const float*)d_in[2];
    const float* qkv_w  = (const float*)d_in[3];
    const float* qkv_b  = (const float*)d_in[4];
    const float* lepe_w = (const float*)d_in[5];
    const float* lepe_b = (const float*)d_in[6];
    const float* g1     = (const float*)d_in[7];
    const float* g2     = (const float*)d_in[8];
    const float* n2g    = (const float*)d_in[9];
    const float* n2b    = (const float*)d_in[10];
    const float* w1     = (const float*)d_in[11];
    const float* b1     = (const float*)d_in[12];
    const float* w2     = (const float*)d_in[13];
    const float* b2     = (const float*)d_in[14];
    float* outp = (float*)d_out;
    char* ws = (char*)d_ws;

    // workspace layout (total ~175 MB)
    u16*   xp_b      = (u16*)(ws + 0);              // 16,777,216 (bf16; region 33 MB)
    u16*   ln1       = (u16*)(ws + 33554432);       // 16,777,216
    u16*   qkv       = (u16*)(ws + 50331648);       // 50,331,648
    u16*   attn_b    = (u16*)(ws + 100663296);      // 16,777,216
    u16*   lepe      = (u16*)(ws + 134217728);      // 16,777,216
    u16*   zbuf      = (u16*)(ws + 150994944);      // 16,777,216
    float* pool_part = (float*)(ws + 167772160);    //  4,194,304
    float* pooled    = (float*)(ws + 171966464);    //    524,288
    float* qk_win    = (float*)(ws + 172490752);    //  1,048,576
    int*   idxb      = (int*)(ws + 173539328);      //      8,192
    u16*   wt_qkv    = (u16*)(ws + 173547520);      //    393,216
    u16*   wt_m1     = (u16*)(ws + 173940736);      //    524,288
    u16*   wt_m2     = (u16*)(ws + 174465024);      //    524,288  (end 174,989,312)
    u16*   hbuf      = ln1;       // [32768][1024] bf16 reuses ln1+qkv region (exactly 64 MB)

    wtrans3_kernel<<<2816, 256, 0, stream>>>(qkv_w, w1, w2, wt_qkv, wt_m1, wt_m2);

    ln_xpose_kernel<<<512, 256, 0, stream>>>(x, n1g, n1b, xp_b, ln1, pool_part);
    pool_reduce_kernel<<<512, 256, 0, stream>>>(pool_part, pooled);
    qkwin_kernel<<<512, 256, 0, stream>>>(pooled, qkv_w, qkv_b, qk_win);
    routing_kernel<<<512, 64, 0, stream>>>(qk_win, idxb);

    gemm_kernel<0><<<dim3(256, 6), 256, 0, stream>>>(
        ln1, wt_qkv, qkv_b, qkv, 32768, 768, 256, nullptr, nullptr, nullptr);

    attn_lepe_kernel<<<dim3(512, 12), 512, 0, stream>>>(
        qkv, idxb, lepe_w, lepe_b, attn_b, lepe);

    resid1_ln2_kernel<<<8192, 256, 0, stream>>>(xp_b, attn_b, lepe, g1, n2g, n2b, xp_b, zbuf);

    gemm_kernel<1><<<dim3(256, 8), 256, 0, stream>>>(
        zbuf, wt_m1, b1, hbuf, 32768, 1024, 256, nullptr, nullptr, nullptr);
    gemm_kernel<2><<<dim3(256, 2), 256, 0, stream>>>(
        hbuf, wt_m2, b2, nullptr, 32768, 256, 1024, xp_b, g2, outp);
}